// Round 2
// baseline (166.115 us; speedup 1.0000x reference)
//
#include <hip/hip_runtime.h>

// ---------------------------------------------------------------------------
// SparseAttention: x@w_qkv+b -> sliding-window attn (w=32) -> @w_out+b
// B=2 S=2048 D=512 H=8 hd=64. All fp32 I/O.
// GEMMs: split-bf16 MFMA (C = Ah*Bh + Al*Bh + Ah*Bl), ~fp32 accurate.
// Attention: fp32 vector ALU, K/V/P staged bf16 (errs ~2e-4 << 3.2e-3 thresh).
// R1 fix: attn_pv thread-tile was 64x128 (copied from scores); output tile is
// 64x64 -> OOB LDS reads + OOB global writes -> NaN. Now 4x4 per thread.
// ---------------------------------------------------------------------------

typedef __bf16 bf16x8 __attribute__((ext_vector_type(8)));
typedef float  f32x4  __attribute__((ext_vector_type(4)));

__device__ __forceinline__ unsigned short f2bf(float f) {
  unsigned int u = __builtin_bit_cast(unsigned int, f);
  u += 0x7FFFu + ((u >> 16) & 1u);          // round-to-nearest-even
  return (unsigned short)(u >> 16);
}
__device__ __forceinline__ float bf2f(unsigned short u) {
  return __builtin_bit_cast(float, ((unsigned int)u) << 16);
}
__device__ __forceinline__ unsigned int pack2(unsigned short a, unsigned short b) {
  return (unsigned int)a | ((unsigned int)b << 16);
}

#define S_LEN 2048
#define BM 128
#define BN 128
#define BK 32

// ---------------------------------------------------------------------------
// Split-bf16 GEMM: C[M][N] = A[M][K] * W[K][N] + bias[N]   (all fp32 global)
// block 256 = 4 waves (2x2), wave tile 64x64 = 4x4 mfma 16x16x32 tiles.
// ---------------------------------------------------------------------------
__global__ __launch_bounds__(256) void gemm_split_bf16(
    const float* __restrict__ A, const float* __restrict__ W,
    const float* __restrict__ bias, float* __restrict__ C,
    int M, int N, int K) {
  __shared__ __align__(16) unsigned short sAh[BM * BK];
  __shared__ __align__(16) unsigned short sAl[BM * BK];
  __shared__ __align__(16) unsigned short sBh[BN * BK];
  __shared__ __align__(16) unsigned short sBl[BN * BK];

  const int t = threadIdx.x;
  const int lane = t & 63;
  const int w = t >> 6;
  const int wm = w >> 1, wn = w & 1;
  const int mBase = blockIdx.y * BM;
  const int nBase = blockIdx.x * BN;

  f32x4 acc[4][4];
#pragma unroll
  for (int i = 0; i < 4; ++i)
#pragma unroll
    for (int j = 0; j < 4; ++j) acc[i][j] = (f32x4){0.f, 0.f, 0.f, 0.f};

  // staging coords
  const int ar  = t >> 3;          // A row group 0..31 (+32*i)
  const int ac4 = (t & 7) * 4;     // A col (float4)
  const int bn  = t & 127;         // B col 0..127
  const int bkh = (t >> 7) * 16;   // B k-half 0 or 16

  const int lane15 = lane & 15;
  const int kg = lane >> 4;        // k-group 0..3
  const bf16x8* pAh = (const bf16x8*)sAh;
  const bf16x8* pAl = (const bf16x8*)sAl;
  const bf16x8* pBh = (const bf16x8*)sBh;
  const bf16x8* pBl = (const bf16x8*)sBl;

  for (int k0 = 0; k0 < K; k0 += BK) {
    // ---- stage A tile (BM x BK) ----
#pragma unroll
    for (int i = 0; i < 4; ++i) {
      int r = ar + 32 * i;
      float4 v = *(const float4*)&A[(size_t)(mBase + r) * K + k0 + ac4];
      unsigned short h0 = f2bf(v.x), h1 = f2bf(v.y), h2 = f2bf(v.z), h3 = f2bf(v.w);
      unsigned short l0 = f2bf(v.x - bf2f(h0)), l1 = f2bf(v.y - bf2f(h1));
      unsigned short l2 = f2bf(v.z - bf2f(h2)), l3 = f2bf(v.w - bf2f(h3));
      *(uint2*)&sAh[r * BK + ac4] = make_uint2(pack2(h0, h1), pack2(h2, h3));
      *(uint2*)&sAl[r * BK + ac4] = make_uint2(pack2(l0, l1), pack2(l2, l3));
    }
    // ---- stage B tile transposed: sB[n][k] ----
    {
      unsigned int hw[8], lw[8];
#pragma unroll
      for (int i = 0; i < 8; ++i) {
        float v0 = W[(size_t)(k0 + bkh + 2 * i) * N + nBase + bn];
        float v1 = W[(size_t)(k0 + bkh + 2 * i + 1) * N + nBase + bn];
        unsigned short h0 = f2bf(v0), h1 = f2bf(v1);
        unsigned short q0 = f2bf(v0 - bf2f(h0)), q1 = f2bf(v1 - bf2f(h1));
        hw[i] = pack2(h0, h1);
        lw[i] = pack2(q0, q1);
      }
      uint4* dh = (uint4*)&sBh[bn * BK + bkh];
      dh[0] = make_uint4(hw[0], hw[1], hw[2], hw[3]);
      dh[1] = make_uint4(hw[4], hw[5], hw[6], hw[7]);
      uint4* dl = (uint4*)&sBl[bn * BK + bkh];
      dl[0] = make_uint4(lw[0], lw[1], lw[2], lw[3]);
      dl[1] = make_uint4(lw[4], lw[5], lw[6], lw[7]);
    }
    __syncthreads();

    // ---- fragments + MFMA ----
    bf16x8 ah[4], al[4], bh[4], bl[4];
#pragma unroll
    for (int mt = 0; mt < 4; ++mt) {
      int r = wm * 64 + mt * 16 + lane15;
      ah[mt] = pAh[r * 4 + kg];
      al[mt] = pAl[r * 4 + kg];
    }
#pragma unroll
    for (int nt = 0; nt < 4; ++nt) {
      int n = wn * 64 + nt * 16 + lane15;
      bh[nt] = pBh[n * 4 + kg];
      bl[nt] = pBl[n * 4 + kg];
    }
#pragma unroll
    for (int mt = 0; mt < 4; ++mt)
#pragma unroll
      for (int nt = 0; nt < 4; ++nt) {
        acc[mt][nt] = __builtin_amdgcn_mfma_f32_16x16x32_bf16(ah[mt], bh[nt], acc[mt][nt], 0, 0, 0);
        acc[mt][nt] = __builtin_amdgcn_mfma_f32_16x16x32_bf16(al[mt], bh[nt], acc[mt][nt], 0, 0, 0);
        acc[mt][nt] = __builtin_amdgcn_mfma_f32_16x16x32_bf16(ah[mt], bl[nt], acc[mt][nt], 0, 0, 0);
      }
    __syncthreads();
  }

  // ---- epilogue: C/D layout col=lane&15, row=(lane>>4)*4+reg ----
  const int lq = lane >> 4;
#pragma unroll
  for (int mt = 0; mt < 4; ++mt) {
    int row0 = mBase + wm * 64 + mt * 16 + lq * 4;
#pragma unroll
    for (int nt = 0; nt < 4; ++nt) {
      int col = nBase + wn * 64 + nt * 16 + lane15;
      float bv = bias[col];
#pragma unroll
      for (int r = 0; r < 4; ++r) {
        C[(size_t)(row0 + r) * N + col] = acc[mt][nt][r] + bv;
      }
    }
  }
}

// ---------------------------------------------------------------------------
// Attention kernel 1: scores + softmax -> normalized P (bf16) to ws.
// block = (b, h, 64-row tile); dense 64x128 band with -1e9 masking.
// 256 threads -> 64 rows x 128 cols, each thread 4 rows x 8 cols.
// ---------------------------------------------------------------------------
__global__ __launch_bounds__(256) void attn_scores(
    const float* __restrict__ qkv, unsigned short* __restrict__ P) {
  const int tile = blockIdx.x, h = blockIdx.y, b = blockIdx.z;
  const int base = tile * 64;

  __shared__ __align__(16) float Qs[64][65];
  __shared__ __align__(16) unsigned short Kt[64][130];  // Kt[d][j]
  __shared__ float red[64][17];
  __shared__ float Mrow[64];
  __shared__ float Sinv[64];

  const int t = threadIdx.x;
  const int l = t & 63, w = t >> 6;

  // stage Q (fp32) and K (bf16, transposed)
#pragma unroll
  for (int i = 0; i < 16; ++i) {
    int s = 4 * i + w;
    Qs[s][l] = qkv[((size_t)b * S_LEN + base + s) * 1536 + h * 64 + l];
  }
#pragma unroll
  for (int i = 0; i < 32; ++i) {
    int j = 4 * i + w;
    int ja = base - 32 + j;
    ja = ja < 0 ? 0 : (ja >= S_LEN ? S_LEN - 1 : ja);
    Kt[l][j] = f2bf(qkv[((size_t)b * S_LEN + ja) * 1536 + 512 + h * 64 + l]);
  }
  __syncthreads();

  const int ty = t >> 4, tx = t & 15;
  const int s0 = ty * 4, j0 = tx * 8;

  float sc[4][8];
#pragma unroll
  for (int i = 0; i < 4; ++i)
#pragma unroll
    for (int c = 0; c < 8; ++c) sc[i][c] = 0.f;

#pragma unroll 4
  for (int d = 0; d < 64; ++d) {
    float qv[4];
#pragma unroll
    for (int i = 0; i < 4; ++i) qv[i] = Qs[s0 + i][d];
#pragma unroll
    for (int c2 = 0; c2 < 4; ++c2) {
      unsigned int kp = *(const unsigned int*)&Kt[d][j0 + 2 * c2];
      float kl = __builtin_bit_cast(float, kp << 16);
      float kh = __builtin_bit_cast(float, kp & 0xFFFF0000u);
#pragma unroll
      for (int i = 0; i < 4; ++i) {
        sc[i][2 * c2]     += qv[i] * kl;
        sc[i][2 * c2 + 1] += qv[i] * kh;
      }
    }
  }

  // scale + mask (matches ref: scale then where(valid, ., -1e9))
#pragma unroll
  for (int i = 0; i < 4; ++i) {
    int s_abs = base + s0 + i;
#pragma unroll
    for (int c = 0; c < 8; ++c) {
      int j_abs = base - 32 + j0 + c;
      int dlt = j_abs - s_abs;
      bool valid = (dlt >= -32) && (dlt <= 32) && (j_abs >= 0) && (j_abs < S_LEN);
      sc[i][c] = valid ? sc[i][c] * 0.125f : -1.0e9f;
    }
  }

  // row max
#pragma unroll
  for (int i = 0; i < 4; ++i) {
    float m = sc[i][0];
#pragma unroll
    for (int c = 1; c < 8; ++c) m = fmaxf(m, sc[i][c]);
    red[s0 + i][tx] = m;
  }
  __syncthreads();
  if (t < 64) {
    float m = red[t][0];
#pragma unroll
    for (int x = 1; x < 16; ++x) m = fmaxf(m, red[t][x]);
    Mrow[t] = m;
  }
  __syncthreads();

  // exp + row sum
#pragma unroll
  for (int i = 0; i < 4; ++i) {
    float m = Mrow[s0 + i];
    float ps = 0.f;
#pragma unroll
    for (int c = 0; c < 8; ++c) {
      float e = __expf(sc[i][c] - m);
      sc[i][c] = e;
      ps += e;
    }
    red[s0 + i][tx] = ps;
  }
  __syncthreads();
  if (t < 64) {
    float s_ = 0.f;
#pragma unroll
    for (int x = 0; x < 16; ++x) s_ += red[t][x];
    Sinv[t] = 1.0f / s_;
  }
  __syncthreads();

  // write normalized P (bf16)
#pragma unroll
  for (int i = 0; i < 4; ++i) {
    float si = Sinv[s0 + i];
    unsigned int* dst =
        (unsigned int*)(P + (((size_t)b * 8 + h) * S_LEN + base + s0 + i) * 128 + j0);
#pragma unroll
    for (int c2 = 0; c2 < 4; ++c2) {
      dst[c2] = pack2(f2bf(sc[i][2 * c2] * si), f2bf(sc[i][2 * c2 + 1] * si));
    }
  }
}

// ---------------------------------------------------------------------------
// Attention kernel 2: O[s][d] = sum_j P[s][j] * V[j][d]  (band of 128 j)
// Output tile 64 rows x 64 cols; 256 threads, each 4 rows x 4 cols.
// ---------------------------------------------------------------------------
__global__ __launch_bounds__(256) void attn_pv(
    const float* __restrict__ qkv, const unsigned short* __restrict__ P,
    float* __restrict__ O) {
  const int tile = blockIdx.x, h = blockIdx.y, b = blockIdx.z;
  const int base = tile * 64;

  __shared__ __align__(16) unsigned short Pp[64][130];
  __shared__ __align__(16) unsigned short Vs[128][66];

  const int t = threadIdx.x;
  const int l = t & 63, w = t >> 6;

  // stage V (bf16)
#pragma unroll
  for (int i = 0; i < 32; ++i) {
    int j = 4 * i + w;
    int ja = base - 32 + j;
    ja = ja < 0 ? 0 : (ja >= S_LEN ? S_LEN - 1 : ja);
    Vs[j][l] = f2bf(qkv[((size_t)b * S_LEN + ja) * 1536 + 1024 + h * 64 + l]);
  }
  // stage P
  const unsigned int* Pg =
      (const unsigned int*)(P + (((size_t)b * 8 + h) * S_LEN + base) * 128);
#pragma unroll
  for (int i = 0; i < 16; ++i) {
    int f = t + 256 * i;
    int s = f >> 6, jw = f & 63;
    *(unsigned int*)&Pp[s][2 * jw] = Pg[s * 64 + jw];
  }
  __syncthreads();

  const int ty = t >> 4, tx = t & 15;
  const int s0 = ty * 4, d0 = tx * 4;   // 64 rows x 64 cols tile

  float o[4][4];
#pragma unroll
  for (int i = 0; i < 4; ++i)
#pragma unroll
    for (int c = 0; c < 4; ++c) o[i][c] = 0.f;

#pragma unroll 4
  for (int j = 0; j < 128; ++j) {
    float p[4];
#pragma unroll
    for (int i = 0; i < 4; ++i) p[i] = bf2f(Pp[s0 + i][j]);
#pragma unroll
    for (int c2 = 0; c2 < 2; ++c2) {
      unsigned int vp = *(const unsigned int*)&Vs[j][d0 + 2 * c2];
      float vl = __builtin_bit_cast(float, vp << 16);
      float vh = __builtin_bit_cast(float, vp & 0xFFFF0000u);
#pragma unroll
      for (int i = 0; i < 4; ++i) {
        o[i][2 * c2]     += p[i] * vl;
        o[i][2 * c2 + 1] += p[i] * vh;
      }
    }
  }

#pragma unroll
  for (int i = 0; i < 4; ++i) {
    float* dst = &O[((size_t)b * S_LEN + base + s0 + i) * 512 + h * 64 + d0];
    *(float4*)dst = make_float4(o[i][0], o[i][1], o[i][2], o[i][3]);
  }
}

// ---------------------------------------------------------------------------
extern "C" void kernel_launch(void* const* d_in, const int* in_sizes, int n_in,
                              void* d_out, int out_size, void* d_ws, size_t ws_size,
                              hipStream_t stream) {
  const float* x     = (const float*)d_in[0];
  const float* w_qkv = (const float*)d_in[1];
  const float* b_qkv = (const float*)d_in[2];
  const float* w_out = (const float*)d_in[3];
  const float* b_out = (const float*)d_in[4];
  float* out = (float*)d_out;

  // workspace layout (needs 40 MB)
  float* qkv = (float*)d_ws;                                        // 4096x1536 f32 = 25165824 B
  unsigned short* P = (unsigned short*)((char*)d_ws + 25165824);    // 2*8*2048*128 bf16 = 8388608 B
  float* aout = (float*)((char*)d_ws + 33554432);                   // 4096x512 f32 = 8388608 B

  // 1) QKV projection: [4096,512] @ [512,1536] + b
  gemm_split_bf16<<<dim3(12, 32), 256, 0, stream>>>(x, w_qkv, b_qkv, qkv, 4096, 1536, 512);
  // 2) scores + softmax -> P
  attn_scores<<<dim3(32, 8, 2), 256, 0, stream>>>(qkv, P);
  // 3) P @ V -> attn_out
  attn_pv<<<dim3(32, 8, 2), 256, 0, stream>>>(qkv, P, aout);
  // 4) output projection: [4096,512] @ [512,512] + b
  gemm_split_bf16<<<dim3(4, 32), 256, 0, stream>>>(aout, w_out, b_out, out, 4096, 512, 512);
}

// Round 3
// 132.154 us; speedup vs baseline: 1.2570x; 1.2570x over previous
//
#include <hip/hip_runtime.h>

// ---------------------------------------------------------------------------
// SparseAttention v3: prep(split/transpose once) -> glds GEMM -> fused attn.
// B=2 S=2048 D=512 H=8 hd=64, fp32 I/O.
// GEMMs: C=(Ah+Al)*Bh 2-product split-bf16 MFMA, pure global_load_lds staging,
// XOR-swizzled LDS (conflict-free b128 fragment reads). 64x128 tiles.
// Attention: single fused kernel, VALU fp32, bf16 K/V/P, shfl softmax.
// ---------------------------------------------------------------------------

typedef __bf16 bf16x8 __attribute__((ext_vector_type(8)));
typedef float  f32x4  __attribute__((ext_vector_type(4)));
typedef unsigned short u16;
typedef unsigned int   u32;

__device__ __forceinline__ u16 f2bf(float f) {
  u32 u = __builtin_bit_cast(u32, f);
  u += 0x7FFFu + ((u >> 16) & 1u);
  return (u16)(u >> 16);
}
__device__ __forceinline__ float bf2f(u16 u) {
  return __builtin_bit_cast(float, ((u32)u) << 16);
}
__device__ __forceinline__ u32 pack2(u16 a, u16 b) {
  return (u32)a | ((u32)b << 16);
}
__device__ __forceinline__ float lo16(u32 u) {
  return __builtin_bit_cast(float, u << 16);
}
__device__ __forceinline__ float hi16(u32 u) {
  return __builtin_bit_cast(float, u & 0xFFFF0000u);
}
__device__ __forceinline__ void glds16(const void* g, void* l) {
  __builtin_amdgcn_global_load_lds(
      (const __attribute__((address_space(1))) void*)g,
      (__attribute__((address_space(3))) void*)l, 16, 0, 0);
}

// ---------------------------------------------------------------------------
// prep_split: f32 -> (hi bf16, lo bf16), elementwise, float4 per thread.
// ---------------------------------------------------------------------------
__global__ __launch_bounds__(256) void prep_split(
    const float4* __restrict__ X, uint2* __restrict__ H, uint2* __restrict__ L,
    int n4) {
  int i = blockIdx.x * 256 + threadIdx.x;
  if (i >= n4) return;
  float4 v = X[i];
  u16 h0 = f2bf(v.x), h1 = f2bf(v.y), h2 = f2bf(v.z), h3 = f2bf(v.w);
  H[i] = make_uint2(pack2(h0, h1), pack2(h2, h3));
  L[i] = make_uint2(pack2(f2bf(v.x - bf2f(h0)), f2bf(v.y - bf2f(h1))),
                    pack2(f2bf(v.z - bf2f(h2)), f2bf(v.w - bf2f(h3))));
}

// ---------------------------------------------------------------------------
// prep_wt: Wt[n][k] = bf16(W[k][n]) — 32x32 tiled transpose + round.
// ---------------------------------------------------------------------------
__global__ __launch_bounds__(256) void prep_wt(
    const float* __restrict__ W, u16* __restrict__ Wt, int K, int N) {
  __shared__ float T[32][33];
  const int n0 = blockIdx.x * 32, k0 = blockIdx.y * 32;
  const int t = threadIdx.x;
  const int r = t >> 3, c = (t & 7) * 4;
  float4 v = *(const float4*)&W[(size_t)(k0 + r) * N + n0 + c];
  T[c][r] = v.x; T[c + 1][r] = v.y; T[c + 2][r] = v.z; T[c + 3][r] = v.w;
  __syncthreads();
  u16 a = f2bf(T[r][c]),     b = f2bf(T[r][c + 1]);
  u16 cc = f2bf(T[r][c + 2]), d = f2bf(T[r][c + 3]);
  *(uint2*)&Wt[(size_t)(n0 + r) * K + k0 + c] = make_uint2(pack2(a, b), pack2(cc, d));
}

// ---------------------------------------------------------------------------
// gemm_2p: C[M][N] = (Ah+Al)[M][512] * Bt[N][512]^T + bias.
// Tile 64x128, BK=32, 4 waves (2x2), wave tile 32x64 = 2x4 mfma tiles.
// Staging: pure global_load_lds (16B/lane), XOR-swizzled quads.
// mode 0: Cf fp32 [M][N].  mode 1 (N=1536): col<512 -> Cf fp32 (Q),
//   512..1023 -> Kb bf16, 1024.. -> Vb bf16 (each [M][512]).
// ---------------------------------------------------------------------------
__global__ __launch_bounds__(256) void gemm_2p(
    const u16* __restrict__ Ah, const u16* __restrict__ Al,
    const u16* __restrict__ Bt, const float* __restrict__ bias,
    float* __restrict__ Cf, u16* __restrict__ Kb, u16* __restrict__ Vb,
    int N, int mode) {
  __shared__ __align__(16) u16 sAh[64 * 32];
  __shared__ __align__(16) u16 sAl[64 * 32];
  __shared__ __align__(16) u16 sBh[128 * 32];

  const int t = threadIdx.x, l = t & 63, w = t >> 6;
  const int wm = w >> 1, wn = w & 1;
  const int mBase = blockIdx.y * 64, nBase = blockIdx.x * 128;

  // ---- staging addresses (lane -> global src, swizzled quad) ----
  const int q  = l >> 2;                       // row-within-16
  const int kq = ((l & 3) ^ ((q >> 1) & 3)) * 8;  // logical k-quad (shorts)
  const int rA = w * 16 + q;
  const u16* gAh = Ah + (size_t)(mBase + rA) * 512 + kq;
  const u16* gAl = Al + (size_t)(mBase + rA) * 512 + kq;
  const u16* gB0 = Bt + (size_t)(nBase + rA) * 512 + kq;        // rows w*16+q
  const u16* gB1 = Bt + (size_t)(nBase + 64 + rA) * 512 + kq;   // rows 64+...
  u16* lAh = sAh + w * 512;
  u16* lAl = sAl + w * 512;
  u16* lB0 = sBh + w * 512;
  u16* lB1 = sBh + (w + 4) * 512;

  // ---- fragment read offsets (shorts), same swizzle ----
  const int r15 = l & 15, kg = l >> 4;
  const int pq = (kg ^ ((r15 >> 1) & 3)) * 8;
  const int aoff0 = (wm * 32 + r15) * 32 + pq;
  const int aoff1 = aoff0 + 16 * 32;
  int boff[4];
#pragma unroll
  for (int nt = 0; nt < 4; ++nt) boff[nt] = (wn * 64 + nt * 16 + r15) * 32 + pq;

  f32x4 acc[2][4];
#pragma unroll
  for (int i = 0; i < 2; ++i)
#pragma unroll
    for (int j = 0; j < 4; ++j) acc[i][j] = (f32x4){0.f, 0.f, 0.f, 0.f};

  for (int k0 = 0; k0 < 512; k0 += 32) {
    glds16(gAh + k0, lAh);
    glds16(gAl + k0, lAl);
    glds16(gB0 + k0, lB0);
    glds16(gB1 + k0, lB1);
    __syncthreads();
    bf16x8 a0 = *(const bf16x8*)(sAh + aoff0);
    bf16x8 a1 = *(const bf16x8*)(sAh + aoff1);
    bf16x8 e0 = *(const bf16x8*)(sAl + aoff0);
    bf16x8 e1 = *(const bf16x8*)(sAl + aoff1);
    bf16x8 b0 = *(const bf16x8*)(sBh + boff[0]);
    bf16x8 b1 = *(const bf16x8*)(sBh + boff[1]);
    bf16x8 b2 = *(const bf16x8*)(sBh + boff[2]);
    bf16x8 b3 = *(const bf16x8*)(sBh + boff[3]);
    acc[0][0] = __builtin_amdgcn_mfma_f32_16x16x32_bf16(a0, b0, acc[0][0], 0, 0, 0);
    acc[0][0] = __builtin_amdgcn_mfma_f32_16x16x32_bf16(e0, b0, acc[0][0], 0, 0, 0);
    acc[0][1] = __builtin_amdgcn_mfma_f32_16x16x32_bf16(a0, b1, acc[0][1], 0, 0, 0);
    acc[0][1] = __builtin_amdgcn_mfma_f32_16x16x32_bf16(e0, b1, acc[0][1], 0, 0, 0);
    acc[0][2] = __builtin_amdgcn_mfma_f32_16x16x32_bf16(a0, b2, acc[0][2], 0, 0, 0);
    acc[0][2] = __builtin_amdgcn_mfma_f32_16x16x32_bf16(e0, b2, acc[0][2], 0, 0, 0);
    acc[0][3] = __builtin_amdgcn_mfma_f32_16x16x32_bf16(a0, b3, acc[0][3], 0, 0, 0);
    acc[0][3] = __builtin_amdgcn_mfma_f32_16x16x32_bf16(e0, b3, acc[0][3], 0, 0, 0);
    acc[1][0] = __builtin_amdgcn_mfma_f32_16x16x32_bf16(a1, b0, acc[1][0], 0, 0, 0);
    acc[1][0] = __builtin_amdgcn_mfma_f32_16x16x32_bf16(e1, b0, acc[1][0], 0, 0, 0);
    acc[1][1] = __builtin_amdgcn_mfma_f32_16x16x32_bf16(a1, b1, acc[1][1], 0, 0, 0);
    acc[1][1] = __builtin_amdgcn_mfma_f32_16x16x32_bf16(e1, b1, acc[1][1], 0, 0, 0);
    acc[1][2] = __builtin_amdgcn_mfma_f32_16x16x32_bf16(a1, b2, acc[1][2], 0, 0, 0);
    acc[1][2] = __builtin_amdgcn_mfma_f32_16x16x32_bf16(e1, b2, acc[1][2], 0, 0, 0);
    acc[1][3] = __builtin_amdgcn_mfma_f32_16x16x32_bf16(a1, b3, acc[1][3], 0, 0, 0);
    acc[1][3] = __builtin_amdgcn_mfma_f32_16x16x32_bf16(e1, b3, acc[1][3], 0, 0, 0);
    __syncthreads();
  }

  // ---- epilogue: C/D layout col=lane&15, row=(lane>>4)*4+reg ----
  const int lq = l >> 4;
#pragma unroll
  for (int mt = 0; mt < 2; ++mt) {
    int row0 = mBase + wm * 32 + mt * 16 + lq * 4;
#pragma unroll
    for (int nt = 0; nt < 4; ++nt) {
      int col = nBase + wn * 64 + nt * 16 + r15;
      float bv = bias[col];
      if (mode == 0) {
#pragma unroll
        for (int r = 0; r < 4; ++r)
          Cf[(size_t)(row0 + r) * N + col] = acc[mt][nt][r] + bv;
      } else {
        int seg = col >> 9, cc = col & 511;
        if (seg == 0) {
#pragma unroll
          for (int r = 0; r < 4; ++r)
            Cf[(size_t)(row0 + r) * 512 + cc] = acc[mt][nt][r] + bv;
        } else if (seg == 1) {
#pragma unroll
          for (int r = 0; r < 4; ++r)
            Kb[(size_t)(row0 + r) * 512 + cc] = f2bf(acc[mt][nt][r] + bv);
        } else {
#pragma unroll
          for (int r = 0; r < 4; ++r)
            Vb[(size_t)(row0 + r) * 512 + cc] = f2bf(acc[mt][nt][r] + bv);
        }
      }
    }
  }
}

// ---------------------------------------------------------------------------
// attn_fused: per (64-row tile, h, b): scores+softmax+PV in one kernel.
// Q fp32 (transposed in LDS), K/V bf16, P bf16 via LDS. Output split h/l bf16.
// ---------------------------------------------------------------------------
__global__ __launch_bounds__(256) void attn_fused(
    const float* __restrict__ Qf, const u16* __restrict__ Kb,
    const u16* __restrict__ Vb, u16* __restrict__ Oh, u16* __restrict__ Ol) {
  const int tile = blockIdx.x, h = blockIdx.y, b = blockIdx.z;
  const int base = tile * 64;
  __shared__ __align__(16) float Qt[64][68];    // Qt[d][s]
  __shared__ __align__(16) u16  Kt[64][136];    // Kt[d][j]
  __shared__ __align__(16) u16  Vs[128][72];    // Vs[j][d]
  __shared__ __align__(16) u16  Pp[64][136];    // Pp[s][j]

  const int t = threadIdx.x, l = t & 63, w = t >> 6;
  const size_t hb = (size_t)b * 2048;

  // ---- stage Q transposed: Qt[d][s] (b128 writes, conflict-uniform) ----
#pragma unroll
  for (int g = 0; g < 4; ++g) {
    int s0w = w * 16 + g * 4;
    float v0 = Qf[(hb + base + s0w + 0) * 512 + h * 64 + l];
    float v1 = Qf[(hb + base + s0w + 1) * 512 + h * 64 + l];
    float v2 = Qf[(hb + base + s0w + 2) * 512 + h * 64 + l];
    float v3 = Qf[(hb + base + s0w + 3) * 512 + h * 64 + l];
    *(f32x4*)&Qt[l][s0w] = (f32x4){v0, v1, v2, v3};
  }
  // ---- stage K transposed: Kt[d][j] ----
#pragma unroll
  for (int g = 0; g < 4; ++g) {
    int j0w = w * 32 + g * 8;
    u32 kk[4];
#pragma unroll
    for (int u2 = 0; u2 < 4; ++u2) {
      int jj = j0w + u2 * 2;
      int ja0 = min(max(base - 32 + jj, 0), 2047);
      int ja1 = min(max(base - 32 + jj + 1, 0), 2047);
      u16 e0 = Kb[(hb + ja0) * 512 + h * 64 + l];
      u16 e1 = Kb[(hb + ja1) * 512 + h * 64 + l];
      kk[u2] = pack2(e0, e1);
    }
    *(uint4*)&Kt[l][j0w] = make_uint4(kk[0], kk[1], kk[2], kk[3]);
  }
  // ---- stage V: Vs[j][d] (uint per thread) ----
  {
    const int rr = t >> 5, cu = t & 31;
#pragma unroll
    for (int i = 0; i < 16; ++i) {
      int j = i * 8 + rr;
      int ja = min(max(base - 32 + j, 0), 2047);
      u32 vv = *(const u32*)&Vb[(hb + ja) * 512 + h * 64 + cu * 2];
      *(u32*)&Vs[j][cu * 2] = vv;
    }
  }
  __syncthreads();

  // ---- phase 1: scores (rows s0..s0+3, cols j0..j0+7 per thread) ----
  const int ty = t >> 4, tx = t & 15;
  const int s0 = ty * 4, j0 = tx * 8;
  float sc[4][8];
#pragma unroll
  for (int i = 0; i < 4; ++i)
#pragma unroll
    for (int c = 0; c < 8; ++c) sc[i][c] = 0.f;

#pragma unroll 2
  for (int d = 0; d < 64; ++d) {
    f32x4 qv = *(const f32x4*)&Qt[d][s0];
    uint4 kp = *(const uint4*)&Kt[d][j0];
    float kf[8];
    kf[0] = lo16(kp.x); kf[1] = hi16(kp.x);
    kf[2] = lo16(kp.y); kf[3] = hi16(kp.y);
    kf[4] = lo16(kp.z); kf[5] = hi16(kp.z);
    kf[6] = lo16(kp.w); kf[7] = hi16(kp.w);
#pragma unroll
    for (int i = 0; i < 4; ++i)
#pragma unroll
      for (int c = 0; c < 8; ++c) sc[i][c] += qv[i] * kf[c];
  }

  // ---- mask + softmax (shfl butterfly over the 16 tx-lanes) ----
  float inv[4];
#pragma unroll
  for (int i = 0; i < 4; ++i) {
    int s_abs = base + s0 + i;
#pragma unroll
    for (int c = 0; c < 8; ++c) {
      int j_abs = base - 32 + j0 + c;
      int dlt = j_abs - s_abs;
      bool valid = (dlt >= -32) && (dlt <= 32) && (j_abs >= 0) && (j_abs < 2048);
      sc[i][c] = valid ? sc[i][c] * 0.125f : -1.0e9f;
    }
    float m = sc[i][0];
#pragma unroll
    for (int c = 1; c < 8; ++c) m = fmaxf(m, sc[i][c]);
#pragma unroll
    for (int msk = 1; msk < 16; msk <<= 1) m = fmaxf(m, __shfl_xor(m, msk, 64));
    float s_ = 0.f;
#pragma unroll
    for (int c = 0; c < 8; ++c) {
      float e = __expf(sc[i][c] - m);
      sc[i][c] = e;
      s_ += e;
    }
#pragma unroll
    for (int msk = 1; msk < 16; msk <<= 1) s_ += __shfl_xor(s_, msk, 64);
    inv[i] = 1.0f / s_;
  }

  // ---- write P (normalized, bf16) ----
#pragma unroll
  for (int i = 0; i < 4; ++i) {
    u32 pk0 = pack2(f2bf(sc[i][0] * inv[i]), f2bf(sc[i][1] * inv[i]));
    u32 pk1 = pack2(f2bf(sc[i][2] * inv[i]), f2bf(sc[i][3] * inv[i]));
    u32 pk2 = pack2(f2bf(sc[i][4] * inv[i]), f2bf(sc[i][5] * inv[i]));
    u32 pk3 = pack2(f2bf(sc[i][6] * inv[i]), f2bf(sc[i][7] * inv[i]));
    *(uint4*)&Pp[s0 + i][j0] = make_uint4(pk0, pk1, pk2, pk3);
  }
  __syncthreads();

  // ---- phase 3: O = P @ V (rows s0..s0+3, cols d0..d0+3 per thread) ----
  const int d0 = tx * 4;
  float o[4][4];
#pragma unroll
  for (int i = 0; i < 4; ++i)
#pragma unroll
    for (int c = 0; c < 4; ++c) o[i][c] = 0.f;

#pragma unroll 2
  for (int jb = 0; jb < 16; ++jb) {
    float pf[4][8];
#pragma unroll
    for (int i = 0; i < 4; ++i) {
      uint4 pw = *(const uint4*)&Pp[s0 + i][jb * 8];
      pf[i][0] = lo16(pw.x); pf[i][1] = hi16(pw.x);
      pf[i][2] = lo16(pw.y); pf[i][3] = hi16(pw.y);
      pf[i][4] = lo16(pw.z); pf[i][5] = hi16(pw.z);
      pf[i][6] = lo16(pw.w); pf[i][7] = hi16(pw.w);
    }
#pragma unroll
    for (int jj = 0; jj < 8; ++jj) {
      uint2 vv = *(const uint2*)&Vs[jb * 8 + jj][d0];
      float v0 = lo16(vv.x), v1 = hi16(vv.x), v2 = lo16(vv.y), v3 = hi16(vv.y);
#pragma unroll
      for (int i = 0; i < 4; ++i) {
        o[i][0] += pf[i][jj] * v0;
        o[i][1] += pf[i][jj] * v1;
        o[i][2] += pf[i][jj] * v2;
        o[i][3] += pf[i][jj] * v3;
      }
    }
  }

  // ---- epilogue: write O split into h/l bf16 ----
#pragma unroll
  for (int i = 0; i < 4; ++i) {
    size_t orow = (hb + base + s0 + i) * 512 + h * 64 + d0;
    u16 h0 = f2bf(o[i][0]), h1 = f2bf(o[i][1]);
    u16 h2 = f2bf(o[i][2]), h3 = f2bf(o[i][3]);
    *(uint2*)&Oh[orow] = make_uint2(pack2(h0, h1), pack2(h2, h3));
    u16 l0 = f2bf(o[i][0] - bf2f(h0)), l1 = f2bf(o[i][1] - bf2f(h1));
    u16 l2 = f2bf(o[i][2] - bf2f(h2)), l3 = f2bf(o[i][3] - bf2f(h3));
    *(uint2*)&Ol[orow] = make_uint2(pack2(l0, l1), pack2(l2, l3));
  }
}

// ---------------------------------------------------------------------------
extern "C" void kernel_launch(void* const* d_in, const int* in_sizes, int n_in,
                              void* d_out, int out_size, void* d_ws, size_t ws_size,
                              hipStream_t stream) {
  const float* x     = (const float*)d_in[0];
  const float* w_qkv = (const float*)d_in[1];
  const float* b_qkv = (const float*)d_in[2];
  const float* w_out = (const float*)d_in[3];
  const float* b_out = (const float*)d_in[4];
  float* out = (float*)d_out;

  // workspace layout (35.7 MB total)
  char* ws = (char*)d_ws;
  float* qf  = (float*)(ws + 0);         // 4096x512 f32   = 8388608
  u16*   kb  = (u16*)(ws + 8388608);     // 4096x512 bf16  = 4194304
  u16*   vb  = (u16*)(ws + 12582912);    // 4194304
  u16*   xh  = (u16*)(ws + 16777216);    // 4194304
  u16*   xl  = (u16*)(ws + 20971520);    // 4194304
  u16*   wqt = (u16*)(ws + 25165824);    // 1536x512 bf16  = 1572864
  u16*   wot = (u16*)(ws + 26738688);    // 512x512 bf16   = 524288
  u16*   aoh = (u16*)(ws + 27262976);    // 4194304
  u16*   aol = (u16*)(ws + 31457280);    // 4194304

  // 1) preps
  prep_split<<<2048, 256, 0, stream>>>((const float4*)x, (uint2*)xh, (uint2*)xl,
                                       4096 * 512 / 4);
  prep_wt<<<dim3(48, 16), 256, 0, stream>>>(w_qkv, wqt, 512, 1536);
  prep_wt<<<dim3(16, 16), 256, 0, stream>>>(w_out, wot, 512, 512);
  // 2) QKV projection (writes Q fp32, K/V bf16)
  gemm_2p<<<dim3(12, 64), 256, 0, stream>>>(xh, xl, wqt, b_qkv, qf, kb, vb,
                                            1536, 1);
  // 3) fused sliding-window attention (writes split h/l bf16)
  attn_fused<<<dim3(32, 8, 2), 256, 0, stream>>>(qf, kb, vb, aoh, aol);
  // 4) output projection
  gemm_2p<<<dim3(4, 64), 256, 0, stream>>>(aoh, aol, wot, b_out, out,
                                           (u16*)qf, (u16*)qf, 512, 0);
}

// Round 5
// 117.329 us; speedup vs baseline: 1.4158x; 1.1264x over previous
//
#include <hip/hip_runtime.h>

// ---------------------------------------------------------------------------
// SparseAttention v4.1: prep(1 kernel) -> 128x128 glds GEMM (QKV, writes
// Q-scaled/K/V bf16) -> full-MFMA fused attention -> 64x128 glds GEMM (out).
// B=2 S=2048 D=512 H=8 hd=64, fp32 I/O.
// GEMMs: C=(Ah+Al)*Bh 2-product split-bf16 MFMA, pure global_load_lds staging,
// XOR-swizzled LDS quads (conflict-free-ish b128 fragment reads).
// Attention: QK^T and PV on matrix cores; softmax via shfl in C-layout;
// P LDS round-trip C-layout -> A-layout (m120 pattern).
// v4.1: MFMA16 macro -> inline function (braced-init-in-macro compile fix).
// ---------------------------------------------------------------------------

typedef __bf16 bf16x8 __attribute__((ext_vector_type(8)));
typedef float  f32x4  __attribute__((ext_vector_type(4)));
typedef unsigned short u16;
typedef unsigned int   u32;

__device__ __forceinline__ u16 f2bf(float f) {
  u32 u = __builtin_bit_cast(u32, f);
  u += 0x7FFFu + ((u >> 16) & 1u);
  return (u16)(u >> 16);
}
__device__ __forceinline__ float bf2f(u16 u) {
  return __builtin_bit_cast(float, ((u32)u) << 16);
}
__device__ __forceinline__ u32 pack2(u16 a, u16 b) {
  return (u32)a | ((u32)b << 16);
}
__device__ __forceinline__ void glds16(const void* g, void* l) {
  __builtin_amdgcn_global_load_lds(
      (const __attribute__((address_space(1))) void*)g,
      (__attribute__((address_space(3))) void*)l, 16, 0, 0);
}
__device__ __forceinline__ f32x4 mfma16(bf16x8 a, bf16x8 b, f32x4 c) {
  return __builtin_amdgcn_mfma_f32_16x16x32_bf16(a, b, c, 0, 0, 0);
}

// ---------------------------------------------------------------------------
// prep_all: one launch. blocks [0,2048): split x into xh/xl.
// [2048,2816): transpose+round w_qkv. [2816,3072): transpose+round w_out.
// ---------------------------------------------------------------------------
__global__ __launch_bounds__(256) void prep_all(
    const float4* __restrict__ X, uint2* __restrict__ XH, uint2* __restrict__ XL,
    const float* __restrict__ Wq, u16* __restrict__ Wqt,
    const float* __restrict__ Wo, u16* __restrict__ Wot) {
  __shared__ float T[32][33];
  const int blk = blockIdx.x, t = threadIdx.x;
  if (blk < 2048) {
    int i = blk * 256 + t;
    float4 v = X[i];
    u16 h0 = f2bf(v.x), h1 = f2bf(v.y), h2 = f2bf(v.z), h3 = f2bf(v.w);
    XH[i] = make_uint2(pack2(h0, h1), pack2(h2, h3));
    XL[i] = make_uint2(pack2(f2bf(v.x - bf2f(h0)), f2bf(v.y - bf2f(h1))),
                       pack2(f2bf(v.z - bf2f(h2)), f2bf(v.w - bf2f(h3))));
    return;
  }
  const float* W;
  u16* Wt;
  int n0, k0, N;
  if (blk < 2816) {
    int idx = blk - 2048;
    W = Wq; Wt = Wqt; N = 1536;
    n0 = (idx % 48) * 32; k0 = (idx / 48) * 32;
  } else {
    int idx = blk - 2816;
    W = Wo; Wt = Wot; N = 512;
    n0 = (idx % 16) * 32; k0 = (idx / 16) * 32;
  }
  const int r = t >> 3, c = (t & 7) * 4;
  float4 v = *(const float4*)&W[(size_t)(k0 + r) * N + n0 + c];
  T[c][r] = v.x; T[c + 1][r] = v.y; T[c + 2][r] = v.z; T[c + 3][r] = v.w;
  __syncthreads();
  u16 a = f2bf(T[r][c]),      b = f2bf(T[r][c + 1]);
  u16 cc = f2bf(T[r][c + 2]), d = f2bf(T[r][c + 3]);
  *(uint2*)&Wt[(size_t)(n0 + r) * 512 + k0 + c] =
      make_uint2(pack2(a, b), pack2(cc, d));
}

// ---------------------------------------------------------------------------
// gemm_qkv: [4096,512](split) @ [512,1536]^T(bf16) + bias.
// 128x128 tile, BK=32, 4 waves 2x2, wave 64x64 = 4x4 mfma, 32 MFMA/wave/iter.
// Epilogue: col<512 -> Qb bf16 *0.125 ; <1024 -> Kb bf16 ; else Vb bf16.
// ---------------------------------------------------------------------------
__global__ __launch_bounds__(256) void gemm_qkv(
    const u16* __restrict__ Ah, const u16* __restrict__ Al,
    const u16* __restrict__ Bt, const float* __restrict__ bias,
    u16* __restrict__ Qb, u16* __restrict__ Kb, u16* __restrict__ Vb) {
  __shared__ __align__(16) u16 sAh[128 * 32];
  __shared__ __align__(16) u16 sAl[128 * 32];
  __shared__ __align__(16) u16 sB[128 * 32];

  const int t = threadIdx.x, l = t & 63, w = t >> 6;
  const int wm = w >> 1, wn = w & 1;
  const int mBase = blockIdx.y * 128, nBase = blockIdx.x * 128;

  // staging: wave w stages rows [w*32, w*32+32) of each region, 2 instr each
  const int q = l >> 2;
  const int kq = ((l & 3) ^ ((q >> 1) & 3)) * 8;
  const int rw0 = w * 32 + q, rw1 = rw0 + 16;
  const u16* gAh0 = Ah + (size_t)(mBase + rw0) * 512 + kq;
  const u16* gAh1 = Ah + (size_t)(mBase + rw1) * 512 + kq;
  const u16* gAl0 = Al + (size_t)(mBase + rw0) * 512 + kq;
  const u16* gAl1 = Al + (size_t)(mBase + rw1) * 512 + kq;
  const u16* gB0  = Bt + (size_t)(nBase + rw0) * 512 + kq;
  const u16* gB1  = Bt + (size_t)(nBase + rw1) * 512 + kq;
  u16* lAh0 = sAh + (w * 32) * 32;
  u16* lAh1 = sAh + (w * 32 + 16) * 32;
  u16* lAl0 = sAl + (w * 32) * 32;
  u16* lAl1 = sAl + (w * 32 + 16) * 32;
  u16* lB0  = sB + (w * 32) * 32;
  u16* lB1  = sB + (w * 32 + 16) * 32;

  // fragment offsets
  const int r15 = l & 15, kg = l >> 4;
  const int pq = (kg ^ ((r15 >> 1) & 3)) * 8;
  int aoff[4], boff[4];
#pragma unroll
  for (int mt = 0; mt < 4; ++mt) aoff[mt] = (wm * 64 + mt * 16 + r15) * 32 + pq;
#pragma unroll
  for (int nt = 0; nt < 4; ++nt) boff[nt] = (wn * 64 + nt * 16 + r15) * 32 + pq;

  f32x4 acc[4][4];
#pragma unroll
  for (int i = 0; i < 4; ++i)
#pragma unroll
    for (int j = 0; j < 4; ++j) acc[i][j] = (f32x4){0.f, 0.f, 0.f, 0.f};

  for (int k0 = 0; k0 < 512; k0 += 32) {
    glds16(gAh0 + k0, lAh0);
    glds16(gAh1 + k0, lAh1);
    glds16(gAl0 + k0, lAl0);
    glds16(gAl1 + k0, lAl1);
    glds16(gB0 + k0, lB0);
    glds16(gB1 + k0, lB1);
    __syncthreads();
    bf16x8 b[4];
#pragma unroll
    for (int nt = 0; nt < 4; ++nt) b[nt] = *(const bf16x8*)(sB + boff[nt]);
#pragma unroll
    for (int mt = 0; mt < 4; ++mt) {
      bf16x8 ah = *(const bf16x8*)(sAh + aoff[mt]);
      bf16x8 al = *(const bf16x8*)(sAl + aoff[mt]);
#pragma unroll
      for (int nt = 0; nt < 4; ++nt) {
        acc[mt][nt] = mfma16(ah, b[nt], acc[mt][nt]);
        acc[mt][nt] = mfma16(al, b[nt], acc[mt][nt]);
      }
    }
    __syncthreads();
  }

  const int lq = l >> 4;
  const int seg = nBase >> 9, colb = nBase & 511;
#pragma unroll
  for (int mt = 0; mt < 4; ++mt) {
    int row0 = mBase + wm * 64 + mt * 16 + lq * 4;
#pragma unroll
    for (int nt = 0; nt < 4; ++nt) {
      int col = wn * 64 + nt * 16 + r15;       // 0..127 within block
      float bv = bias[nBase + col];
      int cc = colb + col;
      if (seg == 0) {
#pragma unroll
        for (int r = 0; r < 4; ++r)
          Qb[(size_t)(row0 + r) * 512 + cc] = f2bf((acc[mt][nt][r] + bv) * 0.125f);
      } else if (seg == 1) {
#pragma unroll
        for (int r = 0; r < 4; ++r)
          Kb[(size_t)(row0 + r) * 512 + cc] = f2bf(acc[mt][nt][r] + bv);
      } else {
#pragma unroll
        for (int r = 0; r < 4; ++r)
          Vb[(size_t)(row0 + r) * 512 + cc] = f2bf(acc[mt][nt][r] + bv);
      }
    }
  }
}

// ---------------------------------------------------------------------------
// attn_mfma: per (64-row tile, h, b). QK^T (64x128x64) and PV (64x64x128)
// on matrix cores. Q pre-scaled bf16. Softmax in C-layout via shfl_xor over
// the 16-lane row group. P: C-layout regs -> LDS [s][j] -> A-frag b128.
// Output split h/l bf16 for the out-projection GEMM.
// ---------------------------------------------------------------------------
__global__ __launch_bounds__(256) void attn_mfma(
    const u16* __restrict__ Qb, const u16* __restrict__ Kb,
    const u16* __restrict__ Vb, u16* __restrict__ Oh, u16* __restrict__ Ol) {
  const int tile = blockIdx.x, h = blockIdx.y, b = blockIdx.z;
  const int base = tile * 64;
  const size_t hb = (size_t)b * 2048;

  __shared__ __align__(16) u16 Qs[64][72];    // [s][d]
  __shared__ __align__(16) u16 Ks[128][72];   // [j][d]
  __shared__ __align__(16) u16 Vt[64][136];   // [d][j]
  __shared__ __align__(16) u16 Pp[64][136];   // [s][j]

  const int t = threadIdx.x, l = t & 63, w = t >> 6;
  const int r15 = l & 15, kg = l >> 4;

  // ---- stage Q (row copy) ----
  {
    int r = t >> 2, c0 = (t & 3) * 16;
    const uint4* src = (const uint4*)&Qb[(hb + base + r) * 512 + h * 64 + c0];
    *(uint4*)&Qs[r][c0] = src[0];
    *(uint4*)&Qs[r][c0 + 8] = src[1];
  }
  // ---- stage K (row copy, clamped band) ----
  {
    int j = t >> 1, half = (t & 1) * 32;
    int ja = min(max(base - 32 + j, 0), 2047);
    const uint4* src = (const uint4*)&Kb[(hb + ja) * 512 + h * 64 + half];
    uint4* dst = (uint4*)&Ks[j][half];
    dst[0] = src[0]; dst[1] = src[1]; dst[2] = src[2]; dst[3] = src[3];
  }
  // ---- stage V transposed: Vt[d][j] ----
  {
    int j = t >> 1, ds = (t & 1) * 32;
    int ja = min(max(base - 32 + j, 0), 2047);
    const u16* src = &Vb[(hb + ja) * 512 + h * 64 + ds];
    u16 tmp[32];
    *(uint4*)&tmp[0]  = *(const uint4*)(src);
    *(uint4*)&tmp[8]  = *(const uint4*)(src + 8);
    *(uint4*)&tmp[16] = *(const uint4*)(src + 16);
    *(uint4*)&tmp[24] = *(const uint4*)(src + 24);
#pragma unroll
    for (int i = 0; i < 32; ++i) Vt[ds + i][j] = tmp[i];
  }
  __syncthreads();

  // ---- QK^T: wave w owns rows [w*16, w*16+16) ----
  bf16x8 aQ0 = *(const bf16x8*)&Qs[w * 16 + r15][kg * 8];
  bf16x8 aQ1 = *(const bf16x8*)&Qs[w * 16 + r15][32 + kg * 8];
  f32x4 zero = (f32x4){0.f, 0.f, 0.f, 0.f};
  f32x4 sacc[8];
#pragma unroll
  for (int nt = 0; nt < 8; ++nt) {
    bf16x8 b0 = *(const bf16x8*)&Ks[nt * 16 + r15][kg * 8];
    bf16x8 b1 = *(const bf16x8*)&Ks[nt * 16 + r15][32 + kg * 8];
    sacc[nt] = mfma16(aQ0, b0, zero);
    sacc[nt] = mfma16(aQ1, b1, sacc[nt]);
  }

  // ---- mask + softmax (C-layout: row = w*16+kg*4+r, col = nt*16+r15) ----
#pragma unroll
  for (int r = 0; r < 4; ++r) {
    int s_abs = base + w * 16 + kg * 4 + r;
    float m = -3.0e38f;
#pragma unroll
    for (int nt = 0; nt < 8; ++nt) {
      int j_abs = base - 32 + nt * 16 + r15;
      int dlt = j_abs - s_abs;
      bool valid = (dlt >= -32) && (dlt <= 32) && (j_abs >= 0) && (j_abs < 2048);
      float v = valid ? sacc[nt][r] : -1.0e9f;
      sacc[nt][r] = v;
      m = fmaxf(m, v);
    }
#pragma unroll
    for (int msk = 1; msk < 16; msk <<= 1) m = fmaxf(m, __shfl_xor(m, msk, 64));
    float s_ = 0.f;
#pragma unroll
    for (int nt = 0; nt < 8; ++nt) {
      float e = __expf(sacc[nt][r] - m);
      sacc[nt][r] = e;
      s_ += e;
    }
#pragma unroll
    for (int msk = 1; msk < 16; msk <<= 1) s_ += __shfl_xor(s_, msk, 64);
    float inv = 1.0f / s_;
#pragma unroll
    for (int nt = 0; nt < 8; ++nt)
      Pp[w * 16 + kg * 4 + r][nt * 16 + r15] = f2bf(sacc[nt][r] * inv);
  }
  __syncthreads();

  // ---- PV: O[s][d], K-dim = j (128) ----
  bf16x8 aP[4];
#pragma unroll
  for (int kt = 0; kt < 4; ++kt)
    aP[kt] = *(const bf16x8*)&Pp[w * 16 + r15][kt * 32 + kg * 8];
  f32x4 oacc[4];
#pragma unroll
  for (int nt = 0; nt < 4; ++nt) oacc[nt] = zero;
#pragma unroll
  for (int nt = 0; nt < 4; ++nt) {
#pragma unroll
    for (int kt = 0; kt < 4; ++kt) {
      bf16x8 bV = *(const bf16x8*)&Vt[nt * 16 + r15][kt * 32 + kg * 8];
      oacc[nt] = mfma16(aP[kt], bV, oacc[nt]);
    }
  }

  // ---- epilogue: write O split h/l bf16 ----
#pragma unroll
  for (int nt = 0; nt < 4; ++nt) {
#pragma unroll
    for (int r = 0; r < 4; ++r) {
      float v = oacc[nt][r];
      size_t idx =
          (hb + base + w * 16 + kg * 4 + r) * 512 + h * 64 + nt * 16 + r15;
      u16 hh = f2bf(v);
      Oh[idx] = hh;
      Ol[idx] = f2bf(v - bf2f(hh));
    }
  }
}

// ---------------------------------------------------------------------------
// gemm_out: [4096,512](split) @ [512,512]^T(bf16) + bias -> fp32 out.
// 64x128 tile (v3 structure), grid (4,64) = 256 blocks.
// ---------------------------------------------------------------------------
__global__ __launch_bounds__(256) void gemm_out(
    const u16* __restrict__ Ah, const u16* __restrict__ Al,
    const u16* __restrict__ Bt, const float* __restrict__ bias,
    float* __restrict__ Cf) {
  __shared__ __align__(16) u16 sAh[64 * 32];
  __shared__ __align__(16) u16 sAl[64 * 32];
  __shared__ __align__(16) u16 sB[128 * 32];

  const int t = threadIdx.x, l = t & 63, w = t >> 6;
  const int wm = w >> 1, wn = w & 1;
  const int mBase = blockIdx.y * 64, nBase = blockIdx.x * 128;

  const int q = l >> 2;
  const int kq = ((l & 3) ^ ((q >> 1) & 3)) * 8;
  const int rA = w * 16 + q;
  const u16* gAh = Ah + (size_t)(mBase + rA) * 512 + kq;
  const u16* gAl = Al + (size_t)(mBase + rA) * 512 + kq;
  const u16* gB0 = Bt + (size_t)(nBase + rA) * 512 + kq;
  const u16* gB1 = Bt + (size_t)(nBase + 64 + rA) * 512 + kq;
  u16* lAh = sAh + w * 512;
  u16* lAl = sAl + w * 512;
  u16* lB0 = sB + w * 512;
  u16* lB1 = sB + (w + 4) * 512;

  const int r15 = l & 15, kg = l >> 4;
  const int pq = (kg ^ ((r15 >> 1) & 3)) * 8;
  const int aoff0 = (wm * 32 + r15) * 32 + pq;
  const int aoff1 = aoff0 + 16 * 32;
  int boff[4];
#pragma unroll
  for (int nt = 0; nt < 4; ++nt) boff[nt] = (wn * 64 + nt * 16 + r15) * 32 + pq;

  f32x4 acc[2][4];
#pragma unroll
  for (int i = 0; i < 2; ++i)
#pragma unroll
    for (int j = 0; j < 4; ++j) acc[i][j] = (f32x4){0.f, 0.f, 0.f, 0.f};

  for (int k0 = 0; k0 < 512; k0 += 32) {
    glds16(gAh + k0, lAh);
    glds16(gAl + k0, lAl);
    glds16(gB0 + k0, lB0);
    glds16(gB1 + k0, lB1);
    __syncthreads();
    bf16x8 a0 = *(const bf16x8*)(sAh + aoff0);
    bf16x8 a1 = *(const bf16x8*)(sAh + aoff1);
    bf16x8 e0 = *(const bf16x8*)(sAl + aoff0);
    bf16x8 e1 = *(const bf16x8*)(sAl + aoff1);
#pragma unroll
    for (int nt = 0; nt < 4; ++nt) {
      bf16x8 bb = *(const bf16x8*)(sB + boff[nt]);
      acc[0][nt] = mfma16(a0, bb, acc[0][nt]);
      acc[0][nt] = mfma16(e0, bb, acc[0][nt]);
      acc[1][nt] = mfma16(a1, bb, acc[1][nt]);
      acc[1][nt] = mfma16(e1, bb, acc[1][nt]);
    }
    __syncthreads();
  }

  const int lq = l >> 4;
#pragma unroll
  for (int mt = 0; mt < 2; ++mt) {
    int row0 = mBase + wm * 32 + mt * 16 + lq * 4;
#pragma unroll
    for (int nt = 0; nt < 4; ++nt) {
      int col = nBase + wn * 64 + nt * 16 + r15;
      float bv = bias[col];
#pragma unroll
      for (int r = 0; r < 4; ++r)
        Cf[(size_t)(row0 + r) * 512 + col] = acc[mt][nt][r] + bv;
    }
  }
}

// ---------------------------------------------------------------------------
extern "C" void kernel_launch(void* const* d_in, const int* in_sizes, int n_in,
                              void* d_out, int out_size, void* d_ws, size_t ws_size,
                              hipStream_t stream) {
  const float* x     = (const float*)d_in[0];
  const float* w_qkv = (const float*)d_in[1];
  const float* b_qkv = (const float*)d_in[2];
  const float* w_out = (const float*)d_in[3];
  const float* b_out = (const float*)d_in[4];
  float* out = (float*)d_out;

  // workspace layout (~31.5 MB)
  char* ws = (char*)d_ws;
  u16* xh  = (u16*)(ws + 0);          // 4096x512 bf16 = 4194304
  u16* xl  = (u16*)(ws + 4194304);    // 4194304
  u16* wqt = (u16*)(ws + 8388608);    // 1536x512 bf16 = 1572864
  u16* wot = (u16*)(ws + 9961472);    // 512x512 bf16  = 524288
  u16* qb  = (u16*)(ws + 10485760);   // 4096x512 bf16 (pre-scaled) = 4194304
  u16* kb  = (u16*)(ws + 14680064);   // 4194304
  u16* vb  = (u16*)(ws + 18874368);   // 4194304
  u16* aoh = (u16*)(ws + 23068672);   // 4194304
  u16* aol = (u16*)(ws + 27262976);   // 4194304

  prep_all<<<3072, 256, 0, stream>>>((const float4*)x, (uint2*)xh, (uint2*)xl,
                                     w_qkv, wqt, w_out, wot);
  gemm_qkv<<<dim3(12, 32), 256, 0, stream>>>(xh, xl, wqt, b_qkv, qb, kb, vb);
  attn_mfma<<<dim3(32, 8, 2), 256, 0, stream>>>(qb, kb, vb, aoh, aol);
  gemm_out<<<dim3(4, 64), 256, 0, stream>>>(aoh, aol, wot, b_out, out);
}